// Round 19
// baseline (57.273 us; speedup 1.0000x reference)
//
#include <hip/hip_runtime.h>

#define NEGV -1.0e12f
constexpr int B = 16, C = 384, Q = 64, D = 2048;
constexpr int PITCH = 40;      // shorts per packed row (80 B, 2-way banks)
constexpr int IST = 8320;      // shorts per 32-k pack image (208 x 40)
constexpr int NT = 96;         // c-rows per k_score block (n-tile)
constexpr int KC = 4;          // split-K chunks (512 k each, 16 steps)
constexpr int SP = 208;        // S3 partial col pitch (shorts)

typedef __attribute__((ext_vector_type(8))) short s16x8;
typedef __attribute__((ext_vector_type(4))) float f32x4;

__device__ __forceinline__ unsigned pkbf(float lo, float hi) {
  unsigned ulo = __builtin_bit_cast(unsigned, lo);
  unsigned uhi = __builtin_bit_cast(unsigned, hi);
  return (uhi & 0xFFFF0000u) | (ulo >> 16);
}
__device__ __forceinline__ float bflo(unsigned u) {
  return __builtin_bit_cast(float, u << 16);
}
__device__ __forceinline__ float bfhi(unsigned u) {
  return __builtin_bit_cast(float, u & 0xFFFF0000u);
}
__device__ __forceinline__ float bfs(unsigned short u) {
  return __builtin_bit_cast(float, ((unsigned)u) << 16);
}

// ---------------- kernel 1: transposed split-K MFMA score GEMM --------------
// Fully self-contained: w-table gathered in prologue (9 planes x 512 f32,
// 18 KB LDS), pack computed in-loop from q, qstats partials accumulated as a
// side product (folded k_prep). Per block: M = 208 pack rows (13 frags),
// N = 96 c-rows, K = 512 (16 steps). flat grid 256 = (n:4)x(kc:4)x(b:16),
// b fastest. 512 thr = 8 waves (4 M-grp x 2 N-grp). 4 LDS buffers, depth-2
// prefetch, 1 barrier/step. bf16 c side-product (cbf) for the tail kernels.
__global__ __launch_bounds__(512, 1) void k_score(
    const float* __restrict__ q, const float* __restrict__ c,
    const float* __restrict__ w_cq, const float* __restrict__ w_c,
    const float* __restrict__ w_q, const float* __restrict__ W_out,
    unsigned short* __restrict__ S3pb, unsigned short* __restrict__ cbf,
    float* __restrict__ qstatsP) {
  const int t = threadIdx.x;
  const int lane = t & 63, wv = t >> 6;
  const int bid = blockIdx.x;
  const int b = bid & 15, kcb = (bid >> 4) & 3, n0g = bid >> 6;
  const int n0 = n0g * NT;
  const int lr = lane & 15, lg = lane >> 4;
  const int mg = wv >> 1, ng = wv & 1;

  __shared__ unsigned short sBp[4][IST];        // 4 x 16640 B (pack)
  __shared__ unsigned short sCp[4][NT * PITCH]; // 4 x 7680 B  (c rows)
  __shared__ float wL[9 * 512];                 // 18 KB w-table (kcb slice)
  // planes: 0=w_cq 1=W3c0 2=W3c1 3=w_c 4=W1c0 5=W1c1 6=w_q 7=W2c0 8=W2c1

  // prologue: gather this kcb's w-table slice (all coalesced)
  {
    const int k = kcb * 512 + t;
    wL[t] = w_cq[k];
    wL[3 * 512 + t] = w_c[k];
    wL[6 * 512 + t] = w_q[k];
    float2 v3 = *(const float2*)(W_out + (size_t)(2 * D + k) * 2);
    wL[512 + t] = v3.x;
    wL[1024 + t] = v3.y;
    float2 v1 = *(const float2*)(W_out + (size_t)k * 2);
    wL[4 * 512 + t] = v1.x;
    wL[5 * 512 + t] = v1.y;
    float2 v2 = *(const float2*)(W_out + (size_t)(D + k) * 2);
    wL[7 * 512 + t] = v2.x;
    wL[8 * 512 + t] = v2.y;
  }
  __syncthreads();  // drains all vm/lgkm: clean slate for counted vmcnt

  const float* cbase = c + ((size_t)b * C + n0) * D + kcb * 512;
  unsigned short* cbf_base = cbf + ((size_t)b * C + n0) * D + kcb * 512;
  const int qi = t >> 3, qkc = (t & 7) * 4;
  const float* qbase = q + ((size_t)b * Q + qi) * D + kcb * 512 + qkc;

  f32x4 acc[4][3];
#pragma unroll
  for (int f = 0; f < 4; ++f)
#pragma unroll
    for (int g = 0; g < 3; ++g) acc[f][g] = f32x4{0.f, 0.f, 0.f, 0.f};
  float aq0 = 0.f, aq1 = 0.f, aq2 = 0.f;  // qstats partial accumulators

  auto loadQ = [&](float4& r, int s) {
    r = *(const float4*)(qbase + s * 32);
  };
  auto loadC = [&](float4* r, int s) {
    const float* base = cbase + s * 32;
    if (wv < 4) {
      int g0 = wv * 128 + lane;
      r[0] = *(const float4*)(base + (size_t)(g0 >> 3) * D + (g0 & 7) * 4);
      int g1 = g0 + 64;
      r[1] = *(const float4*)(base + (size_t)(g1 >> 3) * D + (g1 & 7) * 4);
    } else {
      int g0 = 512 + (wv - 4) * 64 + lane;
      r[0] = *(const float4*)(base + (size_t)(g0 >> 3) * D + (g0 & 7) * 4);
    }
  };
  // pack the 3 q-streams + stats rows into sBp[buf]; accumulate qstats
  auto writeB = [&](int buf, const float4& rq, int s) {
    int ko = s * 32 + qkc;
    float4 w0 = *(const float4*)&wL[ko];
    float4 w1 = *(const float4*)&wL[512 + ko];
    float4 w2 = *(const float4*)&wL[1024 + ko];
    uint2 u;
    u.x = pkbf(rq.x * w0.x, rq.y * w0.y);
    u.y = pkbf(rq.z * w0.z, rq.w * w0.w);
    *(uint2*)&sBp[buf][qi * PITCH + qkc] = u;
    u.x = pkbf(rq.x * w1.x, rq.y * w1.y);
    u.y = pkbf(rq.z * w1.z, rq.w * w1.w);
    *(uint2*)&sBp[buf][(64 + qi) * PITCH + qkc] = u;
    u.x = pkbf(rq.x * w2.x, rq.y * w2.y);
    u.y = pkbf(rq.z * w2.z, rq.w * w2.w);
    *(uint2*)&sBp[buf][(128 + qi) * PITCH + qkc] = u;
    // qstats side-accumulate (planes 6..8)
    float4 w6 = *(const float4*)&wL[6 * 512 + ko];
    float4 w7 = *(const float4*)&wL[7 * 512 + ko];
    float4 w8 = *(const float4*)&wL[8 * 512 + ko];
    aq0 += rq.x * w6.x + rq.y * w6.y + rq.z * w6.z + rq.w * w6.w;
    aq1 += rq.x * w7.x + rq.y * w7.y + rq.z * w7.z + rq.w * w7.w;
    aq2 += rq.x * w8.x + rq.y * w8.y + rq.z * w8.z + rq.w * w8.w;
    if (t < 24) {  // stats rows 192..194 from planes 3..5
      int r = t >> 3, kc2 = (t & 7) * 4;
      float4 wv4 = *(const float4*)&wL[(3 + r) * 512 + s * 32 + kc2];
      uint2 us;
      us.x = pkbf(wv4.x, wv4.y);
      us.y = pkbf(wv4.z, wv4.w);
      *(uint2*)&sBp[buf][(192 + r) * PITCH + kc2] = us;
    }
  };
  auto writeC = [&](int buf, const float4* r, int s) {
    unsigned short* cb = cbf_base + s * 32;
    if (wv < 4) {
      int g0 = wv * 128 + lane;
      uint2 u0 = {pkbf(r[0].x, r[0].y), pkbf(r[0].z, r[0].w)};
      *(uint2*)&sCp[buf][(g0 >> 3) * PITCH + (g0 & 7) * 4] = u0;
      *(uint2*)(cb + (size_t)(g0 >> 3) * D + (g0 & 7) * 4) = u0;
      int g1 = g0 + 64;
      uint2 u1 = {pkbf(r[1].x, r[1].y), pkbf(r[1].z, r[1].w)};
      *(uint2*)&sCp[buf][(g1 >> 3) * PITCH + (g1 & 7) * 4] = u1;
      *(uint2*)(cb + (size_t)(g1 >> 3) * D + (g1 & 7) * 4) = u1;
    } else {
      int g0 = 512 + (wv - 4) * 64 + lane;
      uint2 u0 = {pkbf(r[0].x, r[0].y), pkbf(r[0].z, r[0].w)};
      *(uint2*)&sCp[buf][(g0 >> 3) * PITCH + (g0 & 7) * 4] = u0;
      *(uint2*)(cb + (size_t)(g0 >> 3) * D + (g0 & 7) * 4) = u0;
    }
  };
  auto compute = [&](int buf) {
    s16x8 af[4], bf[3];
#pragma unroll
    for (int f = 0; f < 4; ++f)
      af[f] = *(const s16x8*)&sBp[buf][(mg * 64 + f * 16 + lr) * PITCH +
                                       lg * 8];
#pragma unroll
    for (int g = 0; g < 3; ++g)
      bf[g] = *(const s16x8*)&sCp[buf][((ng * 3 + g) * 16 + lr) * PITCH +
                                       lg * 8];
#pragma unroll
    for (int f = 0; f < 4; ++f)
#pragma unroll
      for (int g = 0; g < 3; ++g)
        acc[f][g] =
            __builtin_amdgcn_mfma_f32_16x16x32_bf16(af[f], bf[g], acc[f][g],
                                                    0, 0, 0);
  };

  // per-wave vm ops per step: loads = C {2,2,1} + q 1 = {3,3,2};
  // stores = cbf {2,2,1}. steady allowed = 2L + 2St; tails = L+2St, 2St.
  auto vmwait2 = [&]() {
    if (wv < 4)
      asm volatile("s_waitcnt vmcnt(10)" ::: "memory");
    else
      asm volatile("s_waitcnt vmcnt(6)" ::: "memory");
  };
  auto vmwait1 = [&]() {
    if (wv < 4)
      asm volatile("s_waitcnt vmcnt(7)" ::: "memory");
    else
      asm volatile("s_waitcnt vmcnt(4)" ::: "memory");
  };
  auto vmwait0 = [&]() {
    if (wv < 4)
      asm volatile("s_waitcnt vmcnt(4)" ::: "memory");
    else
      asm volatile("s_waitcnt vmcnt(2)" ::: "memory");
  };

  float4 rc[4][2], rq[4];
  loadC(rc[0], 0);
  loadQ(rq[0], 0);
  loadC(rc[1], 1);
  loadQ(rq[1], 1);
#pragma unroll
  for (int s = 0; s < 16; ++s) {
    const int cur = s & 3;
    if (s + 2 < 16) {
      loadC(rc[(s + 2) & 3], s + 2);
      loadQ(rq[(s + 2) & 3], s + 2);
      vmwait2();
    } else if (s + 1 < 16) {
      vmwait1();
    } else {
      vmwait0();
    }
    writeB(cur, rq[cur], s);
    writeC(cur, rc[cur], s);
    asm volatile("s_waitcnt lgkmcnt(0)" ::: "memory");
    __builtin_amdgcn_sched_barrier(0);
    __builtin_amdgcn_s_barrier();  // publish buffers(cur); bounds skew to 1
    compute(cur);
    // no trailing barrier: reuse distance 4 steps, skew <= 1 step
  }

  // qstats partial: reduce over the 8 lanes of each qi, write from n-block 0
  for (int m = 1; m < 8; m <<= 1) {
    aq0 += __shfl_xor(aq0, m, 64);
    aq1 += __shfl_xor(aq1, m, 64);
    aq2 += __shfl_xor(aq2, m, 64);
  }
  if (n0g == 0 && (t & 7) == 0) {
    float* p = qstatsP + (((size_t)kcb * B + b) * Q + qi) * 3;
    p[0] = aq0;
    p[1] = aq1;
    p[2] = aq2;
  }

  // epilogue: bf16-pack real frags (mf < 13) to this kc's partial buffer
  const size_t rowbase = ((size_t)kcb * B + b) * C;
#pragma unroll
  for (int f = 0; f < 4; ++f) {
    int mf = mg * 4 + f;
    if (mf < 13) {
#pragma unroll
      for (int g = 0; g < 3; ++g) {
        int n = n0 + (ng * 3 + g) * 16 + lr;
        uint2 pk;
        pk.x = pkbf(acc[f][g][0], acc[f][g][1]);
        pk.y = pkbf(acc[f][g][2], acc[f][g][3]);
        *(uint2*)(S3pb + (rowbase + n) * SP + mf * 16 + lg * 4) = pk;
      }
    }
  }
}

// ---------------- kernel 2: sum partials + row softmax + reductions ---------
__global__ __launch_bounds__(256) void k_soft(
    const unsigned short* __restrict__ S3pb, const float* __restrict__ qstatsP,
    const int* __restrict__ c_len, const int* __restrict__ q_len,
    const float* __restrict__ b_c, const float* __restrict__ b_q,
    const float* __restrict__ b_cq, float* __restrict__ mrow,
    float* __restrict__ out12) {
  const int t = threadIdx.x, lane = t & 63;
  const int rg = blockIdx.x * 4 + (t >> 6);  // b*C + r
  const int b = rg / C, r = rg % C;
  float s_cq = 0.f, sc = 0.f, w10 = 0.f, w11 = 0.f, t30 = 0.f, t31 = 0.f;
  float qs0 = 0.f, qs1 = 0.f, qs2 = 0.f;
#pragma unroll
  for (int p = 0; p < KC; ++p) {
    const unsigned short* Sr = S3pb + ((size_t)p * B * C + rg) * SP;
    s_cq += bfs(Sr[lane]);
    sc += bfs(Sr[192]);
    w10 += bfs(Sr[193]);
    w11 += bfs(Sr[194]);
    t30 += bfs(Sr[64 + lane]);
    t31 += bfs(Sr[128 + lane]);
    const float* qp = qstatsP + (((size_t)p * B + b) * Q + lane) * 3;
    qs0 += qp[0];
    qs1 += qp[1];
    qs2 += qp[2];
  }
  float s = s_cq + sc + qs0 + b_c[0] + b_q[0] + b_cq[0];
  const int cl = c_len[b], ql = q_len[b];
  bool masked = (lane >= ql) || ((r >= cl) && (lane < Q - 1));
  if (masked) s += NEGV;
  float mx = s;
  for (int m = 1; m < 64; m <<= 1) mx = fmaxf(mx, __shfl_xor(mx, m, 64));
  float e = __expf(s - mx);
  float den = e;
  for (int m = 1; m < 64; m <<= 1) den += __shfl_xor(den, m, 64);
  float a = e / den;
  float v0 = a * (qs1 + t30);
  float v1 = a * (qs2 + t31);
  for (int m = 1; m < 64; m <<= 1) {
    v0 += __shfl_xor(v0, m, 64);
    v1 += __shfl_xor(v1, m, 64);
  }
  if (lane == 0) {
    mrow[rg] = mx;
    out12[rg * 2 + 0] = w10 + v0;
    out12[rg * 2 + 1] = w11 + v1;
  }
}

// ---------------- kernel 3: q2c GEMV (bf16 c) fused with W4 -> u vectors ----
__global__ __launch_bounds__(512) void k_q2cu(
    const unsigned short* __restrict__ cbf, const float* __restrict__ mrow,
    const float* __restrict__ W_out, float* __restrict__ uvec) {
  const int ch = blockIdx.x, b = blockIdx.y;
  const int t = threadIdx.x, lane = t & 63, wv = t >> 6;
  __shared__ float batt[C];
  __shared__ float rmx[8], rsm[8];
  __shared__ float redq0[8][64], redq1[8][64];

  float m = (t < C) ? mrow[b * C + t] : -3.0e38f;
  float mx = m;
  for (int o = 1; o < 64; o <<= 1) mx = fmaxf(mx, __shfl_xor(mx, o, 64));
  if (lane == 0) rmx[wv] = mx;
  __syncthreads();
  mx = rmx[0];
#pragma unroll
  for (int i = 1; i < 8; ++i) mx = fmaxf(mx, rmx[i]);
  float e = (t < C) ? __expf(m - mx) : 0.f;
  float sm = e;
  for (int o = 1; o < 64; o <<= 1) sm += __shfl_xor(sm, o, 64);
  if (lane == 0) rsm[wv] = sm;
  __syncthreads();
  sm = rsm[0] + rsm[1] + rsm[2] + rsm[3] + rsm[4] + rsm[5] + rsm[6] + rsm[7];
  if (t < C) batt[t] = e / sm;
  __syncthreads();

  const int d0 = ch * 128 + lane * 2;
  const unsigned short* p = cbf + ((size_t)b * C + wv * 8) * D + d0;
  float A0[8] = {0.f, 0.f, 0.f, 0.f, 0.f, 0.f, 0.f, 0.f};
  float A1[8] = {0.f, 0.f, 0.f, 0.f, 0.f, 0.f, 0.f, 0.f};
#pragma unroll
  for (int r0 = 0; r0 < 384; r0 += 64) {
    const unsigned short* pr = p + (size_t)r0 * D;
    const float* bt = &batt[r0 + wv * 8];
#pragma unroll
    for (int j = 0; j < 8; ++j) {
      unsigned cc = *(const unsigned*)(pr + (size_t)j * D);
      A0[j] += bt[j] * bflo(cc);
      A1[j] += bt[j] * bfhi(cc);
    }
  }
  float s0 = ((A0[0] + A0[1]) + (A0[2] + A0[3])) +
             ((A0[4] + A0[5]) + (A0[6] + A0[7]));
  float s1 = ((A1[0] + A1[1]) + (A1[2] + A1[3])) +
             ((A1[4] + A1[5]) + (A1[6] + A1[7]));
  redq0[wv][lane] = s0;
  redq1[wv][lane] = s1;
  __syncthreads();
  if (t < 64) {
    float q0 = 0.f, q1 = 0.f;
#pragma unroll
    for (int w = 0; w < 8; ++w) {
      q0 += redq0[w][t];
      q1 += redq1[w][t];
    }
    int dd = ch * 128 + t * 2;
    float4 w4 = *(const float4*)(W_out + (size_t)(3 * D + dd) * 2);
    float4 u = {q0 * w4.x, q0 * w4.y, q1 * w4.z, q1 * w4.w};
    *(float4*)(uvec + ((size_t)b * D + dd) * 2) = u;
  }
}

// ---------------- kernel 4: term4 row-dots (bf16 c) + bias + mask + write ---
__global__ __launch_bounds__(512) void k_out(
    const unsigned short* __restrict__ cbf, const float* __restrict__ uvec,
    const float* __restrict__ out12, const float* __restrict__ b_out,
    const int* __restrict__ c_len, float* __restrict__ outp) {
  const int b = blockIdx.y, r0 = blockIdx.x * 8;
  const int t = threadIdx.x, lane = t & 63, wv = t >> 6;
  __shared__ float u_sh[2 * D];  // interleaved {u0,u1} pairs

  {
    const float* src = uvec + (size_t)b * D * 2 + t * 8;
    float4 v0 = *(const float4*)(src);
    float4 v1 = *(const float4*)(src + 4);
    *(float4*)&u_sh[t * 8] = v0;
    *(float4*)&u_sh[t * 8 + 4] = v1;
  }
  __syncthreads();

  const int r = r0 + wv;
  const unsigned short* crow = cbf + ((size_t)b * C + r) * D;
  float o0 = 0.f, o1 = 0.f;
#pragma unroll
  for (int it = 0; it < 16; ++it) {
    int d0 = it * 128 + lane * 2;
    unsigned cc = *(const unsigned*)(crow + d0);
    float c0 = bflo(cc), c1 = bfhi(cc);
    float4 u = *(const float4*)&u_sh[d0 * 2];
    o0 += c0 * u.x + c1 * u.z;
    o1 += c0 * u.y + c1 * u.w;
  }
  for (int o = 1; o < 64; o <<= 1) {
    o0 += __shfl_xor(o0, o, 64);
    o1 += __shfl_xor(o1, o, 64);
  }
  if (lane == 0) {
    const int idx = b * C + r;
    o0 += out12[idx * 2 + 0] + b_out[0];
    o1 += out12[idx * 2 + 1] + b_out[1];
    if (r >= c_len[b] && r < C - 1) { o0 = NEGV; o1 = NEGV; }
    outp[idx] = o0;
    outp[B * C + idx] = o1;
  }
}

extern "C" void kernel_launch(void* const* d_in, const int* in_sizes, int n_in,
                              void* d_out, int out_size, void* d_ws,
                              size_t ws_size, hipStream_t stream) {
  const float* c = (const float*)d_in[0];
  const float* q = (const float*)d_in[1];
  const int* c_len = (const int*)d_in[2];
  const int* q_len = (const int*)d_in[3];
  const float* w_c = (const float*)d_in[4];
  const float* b_c = (const float*)d_in[5];
  const float* w_q = (const float*)d_in[6];
  const float* b_q = (const float*)d_in[7];
  const float* w_cq = (const float*)d_in[8];
  const float* b_cq = (const float*)d_in[9];
  const float* W_out = (const float*)d_in[10];
  const float* b_out = (const float*)d_in[11];
  float* outp = (float*)d_out;

  // ws: S3 partials bf16 (10.2 MB) | qstatsP | smalls | uvec | cbf (25 MB)
  unsigned short* S3pb = (unsigned short*)d_ws;
  const size_t s3_elems = (size_t)KC * B * C * SP;  // 5,111,808 shorts
  float* ws = (float*)(S3pb + s3_elems);
  float* qstatsP = ws;                         // KC*B*Q*3 = 12288
  float* mrow = ws + 12288;                    // B*C    = 6144
  float* out12 = ws + 12288 + 6144;            // B*C*2  = 12288
  float* uvec = ws + 12288 + 6144 + 12288;     // B*D*2  = 65536
  unsigned short* cbf = (unsigned short*)(uvec + 65536);  // B*C*D bf16

  hipLaunchKernelGGL(k_score, dim3(4 * KC * B), dim3(512), 0, stream, q, c,
                     w_cq, w_c, w_q, W_out, S3pb, cbf, qstatsP);
  hipLaunchKernelGGL(k_soft, dim3(B * C / 4), dim3(256), 0, stream, S3pb,
                     qstatsP, c_len, q_len, b_c, b_q, b_cq, mrow, out12);
  hipLaunchKernelGGL(k_q2cu, dim3(16, B), dim3(512), 0, stream, cbf, mrow,
                     W_out, uvec);
  hipLaunchKernelGGL(k_out, dim3(C / 8, B), dim3(512), 0, stream, cbf, uvec,
                     out12, b_out, c_len, outp);
}

// Round 20
// 44.223 us; speedup vs baseline: 1.2951x; 1.2951x over previous
//
#include <hip/hip_runtime.h>

#define NEGV -1.0e12f
constexpr int B = 16, C = 384, Q = 64, D = 2048;
constexpr int PITCH = 40;      // shorts per packed row (80 B, 2-way banks)
constexpr int IST = 8320;      // shorts per 32-k pack image (208 x 40)
constexpr int NT = 96;         // c-rows per k_score block (n-tile)
constexpr int KC = 4;          // split-K chunks (512 k each, 16 steps)
constexpr int SP = 208;        // S3 partial col pitch (shorts)

typedef __attribute__((ext_vector_type(8))) short s16x8;
typedef __attribute__((ext_vector_type(4))) float f32x4;

__device__ __forceinline__ unsigned pkbf(float lo, float hi) {
  unsigned ulo = __builtin_bit_cast(unsigned, lo);
  unsigned uhi = __builtin_bit_cast(unsigned, hi);
  return (uhi & 0xFFFF0000u) | (ulo >> 16);
}
__device__ __forceinline__ float bflo(unsigned u) {
  return __builtin_bit_cast(float, u << 16);
}
__device__ __forceinline__ float bfhi(unsigned u) {
  return __builtin_bit_cast(float, u & 0xFFFF0000u);
}
__device__ __forceinline__ float bfs(unsigned short u) {
  return __builtin_bit_cast(float, ((unsigned)u) << 16);
}

#define GLD_LDS(gsrc, ldst)                                              \
  __builtin_amdgcn_global_load_lds(                                      \
      (const __attribute__((address_space(1))) unsigned*)(gsrc),         \
      (__attribute__((address_space(3))) unsigned*)(ldst), 16, 0, 0)

// ---------------- kernel 0: qstats (blocks 0..1023) + wpack (1024..1035) ----
// wpack planes (f32 x 2048 each): 0=w_cq, 1=W3c0, 2=W3c1, 3=w_c, 4=W1c0,
// 5=W1c1. 48 KB table consumed by k_score's in-loop pack.
__global__ __launch_bounds__(256) void k_prep(
    const float* __restrict__ q, const float* __restrict__ w_q,
    const float* __restrict__ w_cq, const float* __restrict__ w_c,
    const float* __restrict__ W_out, float* __restrict__ qstats,
    float* __restrict__ wpack) {
  const int t = threadIdx.x;
  if (blockIdx.x < 1024) {
    int bi = blockIdx.x;
    const float* qrow = q + (size_t)bi * D;
    float a0 = 0.f, a1 = 0.f, a2 = 0.f;
    for (int d = t * 4; d < D; d += 256 * 4) {
      float4 qv = *(const float4*)(qrow + d);
      float4 wq = *(const float4*)(w_q + d);
      const float* wp = W_out + (size_t)(D + d) * 2;
      float4 wa = *(const float4*)(wp);
      float4 wb = *(const float4*)(wp + 4);
      a0 += qv.x * wq.x + qv.y * wq.y + qv.z * wq.z + qv.w * wq.w;
      a1 += qv.x * wa.x + qv.y * wa.z + qv.z * wb.x + qv.w * wb.z;
      a2 += qv.x * wa.y + qv.y * wa.w + qv.z * wb.y + qv.w * wb.w;
    }
    for (int m = 1; m < 64; m <<= 1) {
      a0 += __shfl_xor(a0, m, 64);
      a1 += __shfl_xor(a1, m, 64);
      a2 += __shfl_xor(a2, m, 64);
    }
    __shared__ float red[3][4];
    int w = t >> 6, lane = t & 63;
    if (lane == 0) { red[0][w] = a0; red[1][w] = a1; red[2][w] = a2; }
    __syncthreads();
    if (t == 0) {
      qstats[bi * 3 + 0] = red[0][0] + red[0][1] + red[0][2] + red[0][3];
      qstats[bi * 3 + 1] = red[1][0] + red[1][1] + red[1][2] + red[1][3];
      qstats[bi * 3 + 2] = red[2][0] + red[2][1] + red[2][2] + red[2][3];
    }
  } else {
    int wb = blockIdx.x - 1024;  // 0..11
    int plane = wb >> 1, half = wb & 1;
    int k = half * 1024 + t * 4;
    float4 v;
    if (plane == 0) {
      v = *(const float4*)(w_cq + k);
    } else if (plane == 3) {
      v = *(const float4*)(w_c + k);
    } else {
      const float* s;
      if (plane == 1)
        s = W_out + (size_t)(2 * D + k) * 2;
      else if (plane == 2)
        s = W_out + (size_t)(2 * D + k) * 2 + 1;
      else if (plane == 4)
        s = W_out + (size_t)k * 2;
      else
        s = W_out + (size_t)k * 2 + 1;
      v = make_float4(s[0], s[2], s[4], s[6]);
    }
    *(float4*)(wpack + plane * 2048 + k) = v;
  }
}

// ---------------- kernel 1: transposed split-K MFMA score GEMM --------------
// Pack computed IN-KERNEL from q (L2-pinned) x wpack (LDS table) -- no bpk
// round-trip. Per block: M = 208 pack rows (13 frags), N = 96 c-rows,
// K = 512 (16 steps). flat grid 256 = (n:4)x(kc:4)x(b:16), b fastest.
// 512 thr = 8 waves (4 M-grp x 2 N-grp). 4 LDS buffers, depth-2 prefetch,
// 1 barrier/step. bf16 c side-product (cbf) for the tail kernels.
__global__ __launch_bounds__(512, 1) void k_score(
    const float* __restrict__ wpack, const float* __restrict__ q,
    const float* __restrict__ c, unsigned short* __restrict__ S3pb,
    unsigned short* __restrict__ cbf) {
  const int t = threadIdx.x;
  const int lane = t & 63, wv = t >> 6;
  const int bid = blockIdx.x;
  const int b = bid & 15, kcb = (bid >> 4) & 3, n0 = (bid >> 6) * NT;
  const int lr = lane & 15, lg = lane >> 4;
  const int mg = wv >> 1, ng = wv & 1;

  __shared__ unsigned short sBp[4][IST];        // 4 x 16640 B (pack)
  __shared__ unsigned short sCp[4][NT * PITCH]; // 4 x 7680 B  (c rows)
  __shared__ float wL[6 * 512];                 // 12 KB w-table (kcb slice)

  // prologue: stage this kcb's w-table slice (plane-major 512 f32 each)
  {
    int p = t >> 7, j4 = (t & 127) * 4;
    GLD_LDS(wpack + p * 2048 + kcb * 512 + j4, wL + p * 512 + j4);
    if (t < 256) {
      int c2 = 512 + t;
      int p2 = c2 >> 7, k4 = (c2 & 127) * 4;
      GLD_LDS(wpack + p2 * 2048 + kcb * 512 + k4, wL + p2 * 512 + k4);
    }
  }
  asm volatile("s_waitcnt vmcnt(0)" ::: "memory");
  __builtin_amdgcn_s_barrier();

  const float* cbase = c + ((size_t)b * C + n0) * D + kcb * 512;
  unsigned short* cbf_base = cbf + ((size_t)b * C + n0) * D + kcb * 512;
  const int qi = t >> 3, qkc = (t & 7) * 4;
  const float* qbase = q + ((size_t)b * Q + qi) * D + kcb * 512 + qkc;

  f32x4 acc[4][3];
#pragma unroll
  for (int f = 0; f < 4; ++f)
#pragma unroll
    for (int g = 0; g < 3; ++g) acc[f][g] = f32x4{0.f, 0.f, 0.f, 0.f};

  auto loadQ = [&](float4& r, int s) {
    r = *(const float4*)(qbase + s * 32);
  };
  auto loadC = [&](float4* r, int s) {
    const float* base = cbase + s * 32;
    if (wv < 4) {
      int g0 = wv * 128 + lane;
      r[0] = *(const float4*)(base + (size_t)(g0 >> 3) * D + (g0 & 7) * 4);
      int g1 = g0 + 64;
      r[1] = *(const float4*)(base + (size_t)(g1 >> 3) * D + (g1 & 7) * 4);
    } else {
      int g0 = 512 + (wv - 4) * 64 + lane;
      r[0] = *(const float4*)(base + (size_t)(g0 >> 3) * D + (g0 & 7) * 4);
    }
  };
  // pack the 3 q-streams + stats rows into sBp[buf]
  auto writeB = [&](int buf, const float4& rq, int s) {
    int ko = s * 32 + qkc;
    float4 w0 = *(const float4*)&wL[ko];
    float4 w1 = *(const float4*)&wL[512 + ko];
    float4 w2 = *(const float4*)&wL[1024 + ko];
    uint2 u;
    u.x = pkbf(rq.x * w0.x, rq.y * w0.y);
    u.y = pkbf(rq.z * w0.z, rq.w * w0.w);
    *(uint2*)&sBp[buf][qi * PITCH + qkc] = u;
    u.x = pkbf(rq.x * w1.x, rq.y * w1.y);
    u.y = pkbf(rq.z * w1.z, rq.w * w1.w);
    *(uint2*)&sBp[buf][(64 + qi) * PITCH + qkc] = u;
    u.x = pkbf(rq.x * w2.x, rq.y * w2.y);
    u.y = pkbf(rq.z * w2.z, rq.w * w2.w);
    *(uint2*)&sBp[buf][(128 + qi) * PITCH + qkc] = u;
    if (t < 24) {  // stats rows 192..194 from planes 3..5
      int r = t >> 3, kc2 = (t & 7) * 4;
      float4 wv4 = *(const float4*)&wL[(3 + r) * 512 + s * 32 + kc2];
      uint2 us;
      us.x = pkbf(wv4.x, wv4.y);
      us.y = pkbf(wv4.z, wv4.w);
      *(uint2*)&sBp[buf][(192 + r) * PITCH + kc2] = us;
    }
  };
  auto writeC = [&](int buf, const float4* r, int s) {
    unsigned short* cb = cbf_base + s * 32;
    if (wv < 4) {
      int g0 = wv * 128 + lane;
      uint2 u0 = {pkbf(r[0].x, r[0].y), pkbf(r[0].z, r[0].w)};
      *(uint2*)&sCp[buf][(g0 >> 3) * PITCH + (g0 & 7) * 4] = u0;
      *(uint2*)(cb + (size_t)(g0 >> 3) * D + (g0 & 7) * 4) = u0;
      int g1 = g0 + 64;
      uint2 u1 = {pkbf(r[1].x, r[1].y), pkbf(r[1].z, r[1].w)};
      *(uint2*)&sCp[buf][(g1 >> 3) * PITCH + (g1 & 7) * 4] = u1;
      *(uint2*)(cb + (size_t)(g1 >> 3) * D + (g1 & 7) * 4) = u1;
    } else {
      int g0 = 512 + (wv - 4) * 64 + lane;
      uint2 u0 = {pkbf(r[0].x, r[0].y), pkbf(r[0].z, r[0].w)};
      *(uint2*)&sCp[buf][(g0 >> 3) * PITCH + (g0 & 7) * 4] = u0;
      *(uint2*)(cb + (size_t)(g0 >> 3) * D + (g0 & 7) * 4) = u0;
    }
  };
  auto compute = [&](int buf) {
    s16x8 af[4], bf[3];
#pragma unroll
    for (int f = 0; f < 4; ++f)
      af[f] = *(const s16x8*)&sBp[buf][(mg * 64 + f * 16 + lr) * PITCH +
                                       lg * 8];
#pragma unroll
    for (int g = 0; g < 3; ++g)
      bf[g] = *(const s16x8*)&sCp[buf][((ng * 3 + g) * 16 + lr) * PITCH +
                                       lg * 8];
#pragma unroll
    for (int f = 0; f < 4; ++f)
#pragma unroll
      for (int g = 0; g < 3; ++g)
        acc[f][g] =
            __builtin_amdgcn_mfma_f32_16x16x32_bf16(af[f], bf[g], acc[f][g],
                                                    0, 0, 0);
  };

  // per-wave vm ops per step: loads = C {2,2,1} + q 1 = {3,3,2};
  // stores = cbf {2,2,1}. steady allowed = 2L + 2St; tails = L+2St, 2St.
  auto vmwait2 = [&]() {
    if (wv < 4)
      asm volatile("s_waitcnt vmcnt(10)" ::: "memory");
    else
      asm volatile("s_waitcnt vmcnt(6)" ::: "memory");
  };
  auto vmwait1 = [&]() {
    if (wv < 4)
      asm volatile("s_waitcnt vmcnt(7)" ::: "memory");
    else
      asm volatile("s_waitcnt vmcnt(4)" ::: "memory");
  };
  auto vmwait0 = [&]() {
    if (wv < 4)
      asm volatile("s_waitcnt vmcnt(4)" ::: "memory");
    else
      asm volatile("s_waitcnt vmcnt(2)" ::: "memory");
  };

  float4 rc[4][2], rq[4];
  loadC(rc[0], 0);
  loadQ(rq[0], 0);
  loadC(rc[1], 1);
  loadQ(rq[1], 1);
#pragma unroll
  for (int s = 0; s < 16; ++s) {
    const int cur = s & 3;
    if (s + 2 < 16) {
      loadC(rc[(s + 2) & 3], s + 2);
      loadQ(rq[(s + 2) & 3], s + 2);
      vmwait2();
    } else if (s + 1 < 16) {
      vmwait1();
    } else {
      vmwait0();
    }
    writeB(cur, rq[cur], s);
    writeC(cur, rc[cur], s);
    asm volatile("s_waitcnt lgkmcnt(0)" ::: "memory");
    __builtin_amdgcn_sched_barrier(0);
    __builtin_amdgcn_s_barrier();  // publish buffers(cur); bounds skew to 1
    compute(cur);
    // no trailing barrier: reuse distance 4 steps, skew <= 1 step
  }

  // epilogue: bf16-pack real frags (mf < 13) to this kc's partial buffer
  const size_t rowbase = ((size_t)kcb * B + b) * C;
#pragma unroll
  for (int f = 0; f < 4; ++f) {
    int mf = mg * 4 + f;
    if (mf < 13) {
#pragma unroll
      for (int g = 0; g < 3; ++g) {
        int n = n0 + (ng * 3 + g) * 16 + lr;
        uint2 pk;
        pk.x = pkbf(acc[f][g][0], acc[f][g][1]);
        pk.y = pkbf(acc[f][g][2], acc[f][g][3]);
        *(uint2*)(S3pb + (rowbase + n) * SP + mf * 16 + lg * 4) = pk;
      }
    }
  }
}

// ---------------- kernel 2: sum partials + row softmax + reductions ---------
__global__ __launch_bounds__(256) void k_soft(
    const unsigned short* __restrict__ S3pb, const float* __restrict__ qstats,
    const int* __restrict__ c_len, const int* __restrict__ q_len,
    const float* __restrict__ b_c, const float* __restrict__ b_q,
    const float* __restrict__ b_cq, float* __restrict__ mrow,
    float* __restrict__ out12) {
  const int t = threadIdx.x, lane = t & 63;
  const int rg = blockIdx.x * 4 + (t >> 6);  // b*C + r
  const int b = rg / C, r = rg % C;
  float s_cq = 0.f, sc = 0.f, w10 = 0.f, w11 = 0.f, t30 = 0.f, t31 = 0.f;
#pragma unroll
  for (int p = 0; p < KC; ++p) {
    const unsigned short* Sr = S3pb + ((size_t)p * B * C + rg) * SP;
    s_cq += bfs(Sr[lane]);
    sc += bfs(Sr[192]);
    w10 += bfs(Sr[193]);
    w11 += bfs(Sr[194]);
    t30 += bfs(Sr[64 + lane]);
    t31 += bfs(Sr[128 + lane]);
  }
  const float qs0 = qstats[((b << 6) + lane) * 3 + 0];
  const float qs1 = qstats[((b << 6) + lane) * 3 + 1];
  const float qs2 = qstats[((b << 6) + lane) * 3 + 2];
  float s = s_cq + sc + qs0 + b_c[0] + b_q[0] + b_cq[0];
  const int cl = c_len[b], ql = q_len[b];
  bool masked = (lane >= ql) || ((r >= cl) && (lane < Q - 1));
  if (masked) s += NEGV;
  float mx = s;
  for (int m = 1; m < 64; m <<= 1) mx = fmaxf(mx, __shfl_xor(mx, m, 64));
  float e = __expf(s - mx);
  float den = e;
  for (int m = 1; m < 64; m <<= 1) den += __shfl_xor(den, m, 64);
  float a = e / den;
  float v0 = a * (qs1 + t30);
  float v1 = a * (qs2 + t31);
  for (int m = 1; m < 64; m <<= 1) {
    v0 += __shfl_xor(v0, m, 64);
    v1 += __shfl_xor(v1, m, 64);
  }
  if (lane == 0) {
    mrow[rg] = mx;
    out12[rg * 2 + 0] = w10 + v0;
    out12[rg * 2 + 1] = w11 + v1;
  }
}

// ---------------- kernel 3: q2c GEMV (bf16 c) fused with W4 -> u vectors ----
__global__ __launch_bounds__(512) void k_q2cu(
    const unsigned short* __restrict__ cbf, const float* __restrict__ mrow,
    const float* __restrict__ W_out, float* __restrict__ uvec) {
  const int ch = blockIdx.x, b = blockIdx.y;
  const int t = threadIdx.x, lane = t & 63, wv = t >> 6;
  __shared__ float batt[C];
  __shared__ float rmx[8], rsm[8];
  __shared__ float redq0[8][64], redq1[8][64];

  float m = (t < C) ? mrow[b * C + t] : -3.0e38f;
  float mx = m;
  for (int o = 1; o < 64; o <<= 1) mx = fmaxf(mx, __shfl_xor(mx, o, 64));
  if (lane == 0) rmx[wv] = mx;
  __syncthreads();
  mx = rmx[0];
#pragma unroll
  for (int i = 1; i < 8; ++i) mx = fmaxf(mx, rmx[i]);
  float e = (t < C) ? __expf(m - mx) : 0.f;
  float sm = e;
  for (int o = 1; o < 64; o <<= 1) sm += __shfl_xor(sm, o, 64);
  if (lane == 0) rsm[wv] = sm;
  __syncthreads();
  sm = rsm[0] + rsm[1] + rsm[2] + rsm[3] + rsm[4] + rsm[5] + rsm[6] + rsm[7];
  if (t < C) batt[t] = e / sm;
  __syncthreads();

  const int d0 = ch * 128 + lane * 2;
  const unsigned short* p = cbf + ((size_t)b * C + wv * 8) * D + d0;
  float A0[8] = {0.f, 0.f, 0.f, 0.f, 0.f, 0.f, 0.f, 0.f};
  float A1[8] = {0.f, 0.f, 0.f, 0.f, 0.f, 0.f, 0.f, 0.f};
#pragma unroll
  for (int r0 = 0; r0 < 384; r0 += 64) {
    const unsigned short* pr = p + (size_t)r0 * D;
    const float* bt = &batt[r0 + wv * 8];
#pragma unroll
    for (int j = 0; j < 8; ++j) {
      unsigned cc = *(const unsigned*)(pr + (size_t)j * D);
      A0[j] += bt[j] * bflo(cc);
      A1[j] += bt[j] * bfhi(cc);
    }
  }
  float s0 = ((A0[0] + A0[1]) + (A0[2] + A0[3])) +
             ((A0[4] + A0[5]) + (A0[6] + A0[7]));
  float s1 = ((A1[0] + A1[1]) + (A1[2] + A1[3])) +
             ((A1[4] + A1[5]) + (A1[6] + A1[7]));
  redq0[wv][lane] = s0;
  redq1[wv][lane] = s1;
  __syncthreads();
  if (t < 64) {
    float q0 = 0.f, q1 = 0.f;
#pragma unroll
    for (int w = 0; w < 8; ++w) {
      q0 += redq0[w][t];
      q1 += redq1[w][t];
    }
    int dd = ch * 128 + t * 2;
    float4 w4 = *(const float4*)(W_out + (size_t)(3 * D + dd) * 2);
    float4 u = {q0 * w4.x, q0 * w4.y, q1 * w4.z, q1 * w4.w};
    *(float4*)(uvec + ((size_t)b * D + dd) * 2) = u;
  }
}

// ---------------- kernel 4: term4 row-dots (bf16 c) + bias + mask + write ---
__global__ __launch_bounds__(512) void k_out(
    const unsigned short* __restrict__ cbf, const float* __restrict__ uvec,
    const float* __restrict__ out12, const float* __restrict__ b_out,
    const int* __restrict__ c_len, float* __restrict__ outp) {
  const int b = blockIdx.y, r0 = blockIdx.x * 8;
  const int t = threadIdx.x, lane = t & 63, wv = t >> 6;
  __shared__ float u_sh[2 * D];  // interleaved {u0,u1} pairs

  {
    const float* src = uvec + (size_t)b * D * 2 + t * 8;
    float4 v0 = *(const float4*)(src);
    float4 v1 = *(const float4*)(src + 4);
    *(float4*)&u_sh[t * 8] = v0;
    *(float4*)&u_sh[t * 8 + 4] = v1;
  }
  __syncthreads();

  const int r = r0 + wv;
  const unsigned short* crow = cbf + ((size_t)b * C + r) * D;
  float o0 = 0.f, o1 = 0.f;
#pragma unroll
  for (int it = 0; it < 16; ++it) {
    int d0 = it * 128 + lane * 2;
    unsigned cc = *(const unsigned*)(crow + d0);
    float c0 = bflo(cc), c1 = bfhi(cc);
    float4 u = *(const float4*)&u_sh[d0 * 2];
    o0 += c0 * u.x + c1 * u.z;
    o1 += c0 * u.y + c1 * u.w;
  }
  for (int o = 1; o < 64; o <<= 1) {
    o0 += __shfl_xor(o0, o, 64);
    o1 += __shfl_xor(o1, o, 64);
  }
  if (lane == 0) {
    const int idx = b * C + r;
    o0 += out12[idx * 2 + 0] + b_out[0];
    o1 += out12[idx * 2 + 1] + b_out[1];
    if (r >= c_len[b] && r < C - 1) { o0 = NEGV; o1 = NEGV; }
    outp[idx] = o0;
    outp[B * C + idx] = o1;
  }
}

extern "C" void kernel_launch(void* const* d_in, const int* in_sizes, int n_in,
                              void* d_out, int out_size, void* d_ws,
                              size_t ws_size, hipStream_t stream) {
  const float* c = (const float*)d_in[0];
  const float* q = (const float*)d_in[1];
  const int* c_len = (const int*)d_in[2];
  const int* q_len = (const int*)d_in[3];
  const float* w_c = (const float*)d_in[4];
  const float* b_c = (const float*)d_in[5];
  const float* w_q = (const float*)d_in[6];
  const float* b_q = (const float*)d_in[7];
  const float* w_cq = (const float*)d_in[8];
  const float* b_cq = (const float*)d_in[9];
  const float* W_out = (const float*)d_in[10];
  const float* b_out = (const float*)d_in[11];
  float* outp = (float*)d_out;

  // ws: wpack (48 KB) | S3 partials bf16 (10.2 MB) | smalls | uvec | cbf (25MB)
  float* wpack = (float*)d_ws;  // 6 * 2048 f32
  unsigned short* S3pb = (unsigned short*)(wpack + 6 * 2048);
  const size_t s3_elems = (size_t)KC * B * C * SP;  // 5,111,808 shorts
  float* ws = (float*)(S3pb + s3_elems);
  float* qstats = ws;                      // B*Q*3  = 3072
  float* mrow = ws + 3072;                 // B*C    = 6144
  float* out12 = ws + 3072 + 6144;         // B*C*2  = 12288
  float* uvec = ws + 3072 + 6144 + 12288;  // B*D*2  = 65536
  unsigned short* cbf = (unsigned short*)(uvec + 65536);  // B*C*D bf16

  hipLaunchKernelGGL(k_prep, dim3(1024 + 12), dim3(256), 0, stream, q, w_q,
                     w_cq, w_c, W_out, qstats, wpack);
  hipLaunchKernelGGL(k_score, dim3(4 * KC * B), dim3(512), 0, stream, wpack,
                     q, c, S3pb, cbf);
  hipLaunchKernelGGL(k_soft, dim3(B * C / 4), dim3(256), 0, stream, S3pb,
                     qstats, c_len, q_len, b_c, b_q, b_cq, mrow, out12);
  hipLaunchKernelGGL(k_q2cu, dim3(16, B), dim3(512), 0, stream, cbf, mrow,
                     W_out, uvec);
  hipLaunchKernelGGL(k_out, dim3(C / 8, B), dim3(512), 0, stream, cbf, uvec,
                     out12, b_out, c_len, outp);
}

// Round 21
// 43.895 us; speedup vs baseline: 1.3048x; 1.0075x over previous
//
#include <hip/hip_runtime.h>

#define NEGV -1.0e12f
constexpr int B = 16, C = 384, Q = 64, D = 2048;
constexpr int PITCH = 40;      // shorts per packed row (80 B, 2-way banks)
constexpr int IST = 8320;      // shorts per 32-k pack image (208 x 40)
constexpr int NT = 96;         // c-rows per k_score block (n-tile)
constexpr int KC = 4;          // split-K chunks (512 k each, 16 steps)
constexpr int SP = 208;        // S3 partial col pitch (shorts)

typedef __attribute__((ext_vector_type(8))) short s16x8;
typedef __attribute__((ext_vector_type(4))) float f32x4;

__device__ __forceinline__ unsigned pkbf(float lo, float hi) {
  unsigned ulo = __builtin_bit_cast(unsigned, lo);
  unsigned uhi = __builtin_bit_cast(unsigned, hi);
  return (uhi & 0xFFFF0000u) | (ulo >> 16);
}
__device__ __forceinline__ float bflo(unsigned u) {
  return __builtin_bit_cast(float, u << 16);
}
__device__ __forceinline__ float bfhi(unsigned u) {
  return __builtin_bit_cast(float, u & 0xFFFF0000u);
}
__device__ __forceinline__ float bfs(unsigned short u) {
  return __builtin_bit_cast(float, ((unsigned)u) << 16);
}

#define GLD_LDS(gsrc, ldst)                                              \
  __builtin_amdgcn_global_load_lds(                                      \
      (const __attribute__((address_space(1))) unsigned*)(gsrc),         \
      (__attribute__((address_space(3))) unsigned*)(ldst), 16, 0, 0)

// ---------------- kernel 0: qstats (blocks 0..1023) + wpack (1024..1035) ----
// wpack planes (f32 x 2048 each): 0=w_cq, 1=W3c0, 2=W3c1, 3=w_c, 4=W1c0,
// 5=W1c1. 48 KB table consumed by k_score's in-loop pack.
__global__ __launch_bounds__(256) void k_prep(
    const float* __restrict__ q, const float* __restrict__ w_q,
    const float* __restrict__ w_cq, const float* __restrict__ w_c,
    const float* __restrict__ W_out, float* __restrict__ qstats,
    float* __restrict__ wpack) {
  const int t = threadIdx.x;
  if (blockIdx.x < 1024) {
    int bi = blockIdx.x;
    const float* qrow = q + (size_t)bi * D;
    float a0 = 0.f, a1 = 0.f, a2 = 0.f;
    for (int d = t * 4; d < D; d += 256 * 4) {
      float4 qv = *(const float4*)(qrow + d);
      float4 wq = *(const float4*)(w_q + d);
      const float* wp = W_out + (size_t)(D + d) * 2;
      float4 wa = *(const float4*)(wp);
      float4 wb = *(const float4*)(wp + 4);
      a0 += qv.x * wq.x + qv.y * wq.y + qv.z * wq.z + qv.w * wq.w;
      a1 += qv.x * wa.x + qv.y * wa.z + qv.z * wb.x + qv.w * wb.z;
      a2 += qv.x * wa.y + qv.y * wa.w + qv.z * wb.y + qv.w * wb.w;
    }
    for (int m = 1; m < 64; m <<= 1) {
      a0 += __shfl_xor(a0, m, 64);
      a1 += __shfl_xor(a1, m, 64);
      a2 += __shfl_xor(a2, m, 64);
    }
    __shared__ float red[3][4];
    int w = t >> 6, lane = t & 63;
    if (lane == 0) { red[0][w] = a0; red[1][w] = a1; red[2][w] = a2; }
    __syncthreads();
    if (t == 0) {
      qstats[bi * 3 + 0] = red[0][0] + red[0][1] + red[0][2] + red[0][3];
      qstats[bi * 3 + 1] = red[1][0] + red[1][1] + red[1][2] + red[1][3];
      qstats[bi * 3 + 2] = red[2][0] + red[2][1] + red[2][2] + red[2][3];
    }
  } else {
    int wb = blockIdx.x - 1024;  // 0..11
    int plane = wb >> 1, half = wb & 1;
    int k = half * 1024 + t * 4;
    float4 v;
    if (plane == 0) {
      v = *(const float4*)(w_cq + k);
    } else if (plane == 3) {
      v = *(const float4*)(w_c + k);
    } else {
      const float* s;
      if (plane == 1)
        s = W_out + (size_t)(2 * D + k) * 2;
      else if (plane == 2)
        s = W_out + (size_t)(2 * D + k) * 2 + 1;
      else if (plane == 4)
        s = W_out + (size_t)k * 2;
      else
        s = W_out + (size_t)k * 2 + 1;
      v = make_float4(s[0], s[2], s[4], s[6]);
    }
    *(float4*)(wpack + plane * 2048 + k) = v;
  }
}

// ---------------- kernel 1: transposed split-K MFMA score GEMM --------------
// Pack computed IN-KERNEL from q (L2-pinned) x wpack (LDS table). Per block:
// M = 208 pack rows (13 frags), N = 96 c-rows, K = 512 (16 steps). flat grid
// 256 = (n:4)x(kc:4)x(b:16), b fastest. 512 thr = 8 waves (4M x 2N).
// 4 LDS buffers, depth-2 register prefetch, 1 barrier/step. No manual vmcnt:
// all staging is reg-based, compiler inserts precise per-register waits
// (manual counts were stalling on cbf stores). setprio around MFMA (T5 --
// waves can skew a step, so role diversity exists).
__global__ __launch_bounds__(512, 1) void k_score(
    const float* __restrict__ wpack, const float* __restrict__ q,
    const float* __restrict__ c, unsigned short* __restrict__ S3pb,
    unsigned short* __restrict__ cbf) {
  const int t = threadIdx.x;
  const int lane = t & 63, wv = t >> 6;
  const int bid = blockIdx.x;
  const int b = bid & 15, kcb = (bid >> 4) & 3, n0 = (bid >> 6) * NT;
  const int lr = lane & 15, lg = lane >> 4;
  const int mg = wv >> 1, ng = wv & 1;

  __shared__ unsigned short sBp[4][IST];        // 4 x 16640 B (pack)
  __shared__ unsigned short sCp[4][NT * PITCH]; // 4 x 7680 B  (c rows)
  __shared__ float wL[6 * 512];                 // 12 KB w-table (kcb slice)

  // prologue: stage this kcb's w-table slice (plane-major 512 f32 each)
  {
    int p = t >> 7, j4 = (t & 127) * 4;
    GLD_LDS(wpack + p * 2048 + kcb * 512 + j4, wL + p * 512 + j4);
    if (t < 256) {
      int c2 = 512 + t;
      int p2 = c2 >> 7, k4 = (c2 & 127) * 4;
      GLD_LDS(wpack + p2 * 2048 + kcb * 512 + k4, wL + p2 * 512 + k4);
    }
  }
  asm volatile("s_waitcnt vmcnt(0)" ::: "memory");
  __builtin_amdgcn_s_barrier();

  const float* cbase = c + ((size_t)b * C + n0) * D + kcb * 512;
  unsigned short* cbf_base = cbf + ((size_t)b * C + n0) * D + kcb * 512;
  const int qi = t >> 3, qkc = (t & 7) * 4;
  const float* qbase = q + ((size_t)b * Q + qi) * D + kcb * 512 + qkc;

  f32x4 acc[4][3];
#pragma unroll
  for (int f = 0; f < 4; ++f)
#pragma unroll
    for (int g = 0; g < 3; ++g) acc[f][g] = f32x4{0.f, 0.f, 0.f, 0.f};

  auto loadQ = [&](float4& r, int s) {
    r = *(const float4*)(qbase + s * 32);
  };
  auto loadC = [&](float4* r, int s) {
    const float* base = cbase + s * 32;
    if (wv < 4) {
      int g0 = wv * 128 + lane;
      r[0] = *(const float4*)(base + (size_t)(g0 >> 3) * D + (g0 & 7) * 4);
      int g1 = g0 + 64;
      r[1] = *(const float4*)(base + (size_t)(g1 >> 3) * D + (g1 & 7) * 4);
    } else {
      int g0 = 512 + (wv - 4) * 64 + lane;
      r[0] = *(const float4*)(base + (size_t)(g0 >> 3) * D + (g0 & 7) * 4);
    }
  };
  // pack the 3 q-streams + stats rows into sBp[buf]
  auto writeB = [&](int buf, const float4& rq, int s) {
    int ko = s * 32 + qkc;
    float4 w0 = *(const float4*)&wL[ko];
    float4 w1 = *(const float4*)&wL[512 + ko];
    float4 w2 = *(const float4*)&wL[1024 + ko];
    uint2 u;
    u.x = pkbf(rq.x * w0.x, rq.y * w0.y);
    u.y = pkbf(rq.z * w0.z, rq.w * w0.w);
    *(uint2*)&sBp[buf][qi * PITCH + qkc] = u;
    u.x = pkbf(rq.x * w1.x, rq.y * w1.y);
    u.y = pkbf(rq.z * w1.z, rq.w * w1.w);
    *(uint2*)&sBp[buf][(64 + qi) * PITCH + qkc] = u;
    u.x = pkbf(rq.x * w2.x, rq.y * w2.y);
    u.y = pkbf(rq.z * w2.z, rq.w * w2.w);
    *(uint2*)&sBp[buf][(128 + qi) * PITCH + qkc] = u;
    if (t < 24) {  // stats rows 192..194 from planes 3..5
      int r = t >> 3, kc2 = (t & 7) * 4;
      float4 wv4 = *(const float4*)&wL[(3 + r) * 512 + s * 32 + kc2];
      uint2 us;
      us.x = pkbf(wv4.x, wv4.y);
      us.y = pkbf(wv4.z, wv4.w);
      *(uint2*)&sBp[buf][(192 + r) * PITCH + kc2] = us;
    }
  };
  auto writeC = [&](int buf, const float4* r, int s) {
    unsigned short* cb = cbf_base + s * 32;
    if (wv < 4) {
      int g0 = wv * 128 + lane;
      uint2 u0 = {pkbf(r[0].x, r[0].y), pkbf(r[0].z, r[0].w)};
      *(uint2*)&sCp[buf][(g0 >> 3) * PITCH + (g0 & 7) * 4] = u0;
      *(uint2*)(cb + (size_t)(g0 >> 3) * D + (g0 & 7) * 4) = u0;
      int g1 = g0 + 64;
      uint2 u1 = {pkbf(r[1].x, r[1].y), pkbf(r[1].z, r[1].w)};
      *(uint2*)&sCp[buf][(g1 >> 3) * PITCH + (g1 & 7) * 4] = u1;
      *(uint2*)(cb + (size_t)(g1 >> 3) * D + (g1 & 7) * 4) = u1;
    } else {
      int g0 = 512 + (wv - 4) * 64 + lane;
      uint2 u0 = {pkbf(r[0].x, r[0].y), pkbf(r[0].z, r[0].w)};
      *(uint2*)&sCp[buf][(g0 >> 3) * PITCH + (g0 & 7) * 4] = u0;
      *(uint2*)(cb + (size_t)(g0 >> 3) * D + (g0 & 7) * 4) = u0;
    }
  };
  auto compute = [&](int buf) {
    s16x8 af[4], bf[3];
#pragma unroll
    for (int f = 0; f < 4; ++f)
      af[f] = *(const s16x8*)&sBp[buf][(mg * 64 + f * 16 + lr) * PITCH +
                                       lg * 8];
#pragma unroll
    for (int g = 0; g < 3; ++g)
      bf[g] = *(const s16x8*)&sCp[buf][((ng * 3 + g) * 16 + lr) * PITCH +
                                       lg * 8];
    __builtin_amdgcn_s_setprio(1);
#pragma unroll
    for (int f = 0; f < 4; ++f)
#pragma unroll
      for (int g = 0; g < 3; ++g)
        acc[f][g] =
            __builtin_amdgcn_mfma_f32_16x16x32_bf16(af[f], bf[g], acc[f][g],
                                                    0, 0, 0);
    __builtin_amdgcn_s_setprio(0);
  };

  float4 rc[4][2], rq[4];
  loadC(rc[0], 0);
  loadQ(rq[0], 0);
  loadC(rc[1], 1);
  loadQ(rq[1], 1);
#pragma unroll
  for (int s = 0; s < 16; ++s) {
    const int cur = s & 3;
    if (s + 2 < 16) {
      loadC(rc[(s + 2) & 3], s + 2);
      loadQ(rq[(s + 2) & 3], s + 2);
    }
    // no manual vmcnt: writeB/writeC consume registers, compiler inserts
    // exact waits; cbf stores are never waited on.
    writeB(cur, rq[cur], s);
    writeC(cur, rc[cur], s);
    asm volatile("s_waitcnt lgkmcnt(0)" ::: "memory");
    __builtin_amdgcn_sched_barrier(0);
    __builtin_amdgcn_s_barrier();  // publish buffers(cur); bounds skew to 1
    compute(cur);
    // no trailing barrier: reuse distance 4 steps, skew <= 1 step
  }

  // epilogue: bf16-pack real frags (mf < 13) to this kc's partial buffer
  const size_t rowbase = ((size_t)kcb * B + b) * C;
#pragma unroll
  for (int f = 0; f < 4; ++f) {
    int mf = mg * 4 + f;
    if (mf < 13) {
#pragma unroll
      for (int g = 0; g < 3; ++g) {
        int n = n0 + (ng * 3 + g) * 16 + lr;
        uint2 pk;
        pk.x = pkbf(acc[f][g][0], acc[f][g][1]);
        pk.y = pkbf(acc[f][g][2], acc[f][g][3]);
        *(uint2*)(S3pb + (rowbase + n) * SP + mf * 16 + lg * 4) = pk;
      }
    }
  }
}

// ---------------- kernel 2: sum partials + row softmax + reductions ---------
__global__ __launch_bounds__(256) void k_soft(
    const unsigned short* __restrict__ S3pb, const float* __restrict__ qstats,
    const int* __restrict__ c_len, const int* __restrict__ q_len,
    const float* __restrict__ b_c, const float* __restrict__ b_q,
    const float* __restrict__ b_cq, float* __restrict__ mrow,
    float* __restrict__ out12) {
  const int t = threadIdx.x, lane = t & 63;
  const int rg = blockIdx.x * 4 + (t >> 6);  // b*C + r
  const int b = rg / C, r = rg % C;
  float s_cq = 0.f, sc = 0.f, w10 = 0.f, w11 = 0.f, t30 = 0.f, t31 = 0.f;
#pragma unroll
  for (int p = 0; p < KC; ++p) {
    const unsigned short* Sr = S3pb + ((size_t)p * B * C + rg) * SP;
    s_cq += bfs(Sr[lane]);
    sc += bfs(Sr[192]);
    w10 += bfs(Sr[193]);
    w11 += bfs(Sr[194]);
    t30 += bfs(Sr[64 + lane]);
    t31 += bfs(Sr[128 + lane]);
  }
  const float qs0 = qstats[((b << 6) + lane) * 3 + 0];
  const float qs1 = qstats[((b << 6) + lane) * 3 + 1];
  const float qs2 = qstats[((b << 6) + lane) * 3 + 2];
  float s = s_cq + sc + qs0 + b_c[0] + b_q[0] + b_cq[0];
  const int cl = c_len[b], ql = q_len[b];
  bool masked = (lane >= ql) || ((r >= cl) && (lane < Q - 1));
  if (masked) s += NEGV;
  float mx = s;
  for (int m = 1; m < 64; m <<= 1) mx = fmaxf(mx, __shfl_xor(mx, m, 64));
  float e = __expf(s - mx);
  float den = e;
  for (int m = 1; m < 64; m <<= 1) den += __shfl_xor(den, m, 64);
  float a = e / den;
  float v0 = a * (qs1 + t30);
  float v1 = a * (qs2 + t31);
  for (int m = 1; m < 64; m <<= 1) {
    v0 += __shfl_xor(v0, m, 64);
    v1 += __shfl_xor(v1, m, 64);
  }
  if (lane == 0) {
    mrow[rg] = mx;
    out12[rg * 2 + 0] = w10 + v0;
    out12[rg * 2 + 1] = w11 + v1;
  }
}

// ---------------- kernel 3: q2c GEMV (bf16 c) fused with W4 -> u vectors ----
__global__ __launch_bounds__(512) void k_q2cu(
    const unsigned short* __restrict__ cbf, const float* __restrict__ mrow,
    const float* __restrict__ W_out, float* __restrict__ uvec) {
  const int ch = blockIdx.x, b = blockIdx.y;
  const int t = threadIdx.x, lane = t & 63, wv = t >> 6;
  __shared__ float batt[C];
  __shared__ float rmx[8], rsm[8];
  __shared__ float redq0[8][64], redq1[8][64];

  float m = (t < C) ? mrow[b * C + t] : -3.0e38f;
  float mx = m;
  for (int o = 1; o < 64; o <<= 1) mx = fmaxf(mx, __shfl_xor(mx, o, 64));
  if (lane == 0) rmx[wv] = mx;
  __syncthreads();
  mx = rmx[0];
#pragma unroll
  for (int i = 1; i < 8; ++i) mx = fmaxf(mx, rmx[i]);
  float e = (t < C) ? __expf(m - mx) : 0.f;
  float sm = e;
  for (int o = 1; o < 64; o <<= 1) sm += __shfl_xor(sm, o, 64);
  if (lane == 0) rsm[wv] = sm;
  __syncthreads();
  sm = rsm[0] + rsm[1] + rsm[2] + rsm[3] + rsm[4] + rsm[5] + rsm[6] + rsm[7];
  if (t < C) batt[t] = e / sm;
  __syncthreads();

  const int d0 = ch * 128 + lane * 2;
  const unsigned short* p = cbf + ((size_t)b * C + wv * 8) * D + d0;
  float A0[8] = {0.f, 0.f, 0.f, 0.f, 0.f, 0.f, 0.f, 0.f};
  float A1[8] = {0.f, 0.f, 0.f, 0.f, 0.f, 0.f, 0.f, 0.f};
#pragma unroll
  for (int r0 = 0; r0 < 384; r0 += 64) {
    const unsigned short* pr = p + (size_t)r0 * D;
    const float* bt = &batt[r0 + wv * 8];
#pragma unroll
    for (int j = 0; j < 8; ++j) {
      unsigned cc = *(const unsigned*)(pr + (size_t)j * D);
      A0[j] += bt[j] * bflo(cc);
      A1[j] += bt[j] * bfhi(cc);
    }
  }
  float s0 = ((A0[0] + A0[1]) + (A0[2] + A0[3])) +
             ((A0[4] + A0[5]) + (A0[6] + A0[7]));
  float s1 = ((A1[0] + A1[1]) + (A1[2] + A1[3])) +
             ((A1[4] + A1[5]) + (A1[6] + A1[7]));
  redq0[wv][lane] = s0;
  redq1[wv][lane] = s1;
  __syncthreads();
  if (t < 64) {
    float q0 = 0.f, q1 = 0.f;
#pragma unroll
    for (int w = 0; w < 8; ++w) {
      q0 += redq0[w][t];
      q1 += redq1[w][t];
    }
    int dd = ch * 128 + t * 2;
    float4 w4 = *(const float4*)(W_out + (size_t)(3 * D + dd) * 2);
    float4 u = {q0 * w4.x, q0 * w4.y, q1 * w4.z, q1 * w4.w};
    *(float4*)(uvec + ((size_t)b * D + dd) * 2) = u;
  }
}

// ---------------- kernel 4: term4 row-dots (bf16 c) + bias + mask + write ---
__global__ __launch_bounds__(512) void k_out(
    const unsigned short* __restrict__ cbf, const float* __restrict__ uvec,
    const float* __restrict__ out12, const float* __restrict__ b_out,
    const int* __restrict__ c_len, float* __restrict__ outp) {
  const int b = blockIdx.y, r0 = blockIdx.x * 8;
  const int t = threadIdx.x, lane = t & 63, wv = t >> 6;
  __shared__ float u_sh[2 * D];  // interleaved {u0,u1} pairs

  {
    const float* src = uvec + (size_t)b * D * 2 + t * 8;
    float4 v0 = *(const float4*)(src);
    float4 v1 = *(const float4*)(src + 4);
    *(float4*)&u_sh[t * 8] = v0;
    *(float4*)&u_sh[t * 8 + 4] = v1;
  }
  __syncthreads();

  const int r = r0 + wv;
  const unsigned short* crow = cbf + ((size_t)b * C + r) * D;
  float o0 = 0.f, o1 = 0.f;
#pragma unroll
  for (int it = 0; it < 16; ++it) {
    int d0 = it * 128 + lane * 2;
    unsigned cc = *(const unsigned*)(crow + d0);
    float c0 = bflo(cc), c1 = bfhi(cc);
    float4 u = *(const float4*)&u_sh[d0 * 2];
    o0 += c0 * u.x + c1 * u.z;
    o1 += c0 * u.y + c1 * u.w;
  }
  for (int o = 1; o < 64; o <<= 1) {
    o0 += __shfl_xor(o0, o, 64);
    o1 += __shfl_xor(o1, o, 64);
  }
  if (lane == 0) {
    const int idx = b * C + r;
    o0 += out12[idx * 2 + 0] + b_out[0];
    o1 += out12[idx * 2 + 1] + b_out[1];
    if (r >= c_len[b] && r < C - 1) { o0 = NEGV; o1 = NEGV; }
    outp[idx] = o0;
    outp[B * C + idx] = o1;
  }
}

extern "C" void kernel_launch(void* const* d_in, const int* in_sizes, int n_in,
                              void* d_out, int out_size, void* d_ws,
                              size_t ws_size, hipStream_t stream) {
  const float* c = (const float*)d_in[0];
  const float* q = (const float*)d_in[1];
  const int* c_len = (const int*)d_in[2];
  const int* q_len = (const int*)d_in[3];
  const float* w_c = (const float*)d_in[4];
  const float* b_c = (const float*)d_in[5];
  const float* w_q = (const float*)d_in[6];
  const float* b_q = (const float*)d_in[7];
  const float* w_cq = (const float*)d_in[8];
  const float* b_cq = (const float*)d_in[9];
  const float* W_out = (const float*)d_in[10];
  const float* b_out = (const float*)d_in[11];
  float* outp = (float*)d_out;

  // ws: wpack (48 KB) | S3 partials bf16 (10.2 MB) | smalls | uvec | cbf (25MB)
  float* wpack = (float*)d_ws;  // 6 * 2048 f32
  unsigned short* S3pb = (unsigned short*)(wpack + 6 * 2048);
  const size_t s3_elems = (size_t)KC * B * C * SP;  // 5,111,808 shorts
  float* ws = (float*)(S3pb + s3_elems);
  float* qstats = ws;                      // B*Q*3  = 3072
  float* mrow = ws + 3072;                 // B*C    = 6144
  float* out12 = ws + 3072 + 6144;         // B*C*2  = 12288
  float* uvec = ws + 3072 + 6144 + 12288;  // B*D*2  = 65536
  unsigned short* cbf = (unsigned short*)(uvec + 65536);  // B*C*D bf16

  hipLaunchKernelGGL(k_prep, dim3(1024 + 12), dim3(256), 0, stream, q, w_q,
                     w_cq, w_c, W_out, qstats, wpack);
  hipLaunchKernelGGL(k_score, dim3(4 * KC * B), dim3(512), 0, stream, wpack,
                     q, c, S3pb, cbf);
  hipLaunchKernelGGL(k_soft, dim3(B * C / 4), dim3(256), 0, stream, S3pb,
                     qstats, c_len, q_len, b_c, b_q, b_cq, mrow, out12);
  hipLaunchKernelGGL(k_q2cu, dim3(16, B), dim3(512), 0, stream, cbf, mrow,
                     W_out, uvec);
  hipLaunchKernelGGL(k_out, dim3(C / 8, B), dim3(512), 0, stream, cbf, uvec,
                     out12, b_out, c_len, outp);
}

// Round 22
// 39.818 us; speedup vs baseline: 1.4384x; 1.1024x over previous
//
#include <hip/hip_runtime.h>

#define NEGV -1.0e12f
constexpr int B = 16, C = 384, Q = 64, D = 2048;
constexpr int PITCH = 40;      // shorts per packed row (80 B, 2-way banks)
constexpr int IST = 8320;      // shorts per 32-k pack image (208 x 40)
constexpr int NT = 96;         // c-rows per k_score block (n-tile)
constexpr int KC = 4;          // split-K chunks (512 k each, 16 steps)
constexpr int SP = 208;        // S3 partial col pitch (shorts)

typedef __attribute__((ext_vector_type(8))) short s16x8;
typedef __attribute__((ext_vector_type(4))) float f32x4;
typedef __attribute__((ext_vector_type(2))) float f32x2;

__device__ __forceinline__ unsigned pkbf(float lo, float hi) {
  unsigned ulo = __builtin_bit_cast(unsigned, lo);
  unsigned uhi = __builtin_bit_cast(unsigned, hi);
  return (uhi & 0xFFFF0000u) | (ulo >> 16);
}
__device__ __forceinline__ float bfs(unsigned short u) {
  return __builtin_bit_cast(float, ((unsigned)u) << 16);
}
__device__ __forceinline__ unsigned pk8(const float4& v) {
  int p = __builtin_amdgcn_cvt_pk_fp8_f32(v.x, v.y, 0, false);
  p = __builtin_amdgcn_cvt_pk_fp8_f32(v.z, v.w, p, true);
  return (unsigned)p;
}

#define GLD_LDS(gsrc, ldst)                                              \
  __builtin_amdgcn_global_load_lds(                                      \
      (const __attribute__((address_space(1))) unsigned*)(gsrc),         \
      (__attribute__((address_space(3))) unsigned*)(ldst), 16, 0, 0)

// ---------------- kernel 0: qstats (blocks 0..1023) + wpack (1024..1035) ----
__global__ __launch_bounds__(256) void k_prep(
    const float* __restrict__ q, const float* __restrict__ w_q,
    const float* __restrict__ w_cq, const float* __restrict__ w_c,
    const float* __restrict__ W_out, float* __restrict__ qstats,
    float* __restrict__ wpack) {
  const int t = threadIdx.x;
  if (blockIdx.x < 1024) {
    int bi = blockIdx.x;
    const float* qrow = q + (size_t)bi * D;
    float a0 = 0.f, a1 = 0.f, a2 = 0.f;
    for (int d = t * 4; d < D; d += 256 * 4) {
      float4 qv = *(const float4*)(qrow + d);
      float4 wq = *(const float4*)(w_q + d);
      const float* wp = W_out + (size_t)(D + d) * 2;
      float4 wa = *(const float4*)(wp);
      float4 wb = *(const float4*)(wp + 4);
      a0 += qv.x * wq.x + qv.y * wq.y + qv.z * wq.z + qv.w * wq.w;
      a1 += qv.x * wa.x + qv.y * wa.z + qv.z * wb.x + qv.w * wb.z;
      a2 += qv.x * wa.y + qv.y * wa.w + qv.z * wb.y + qv.w * wb.w;
    }
    for (int m = 1; m < 64; m <<= 1) {
      a0 += __shfl_xor(a0, m, 64);
      a1 += __shfl_xor(a1, m, 64);
      a2 += __shfl_xor(a2, m, 64);
    }
    __shared__ float red[3][4];
    int w = t >> 6, lane = t & 63;
    if (lane == 0) { red[0][w] = a0; red[1][w] = a1; red[2][w] = a2; }
    __syncthreads();
    if (t == 0) {
      qstats[bi * 3 + 0] = red[0][0] + red[0][1] + red[0][2] + red[0][3];
      qstats[bi * 3 + 1] = red[1][0] + red[1][1] + red[1][2] + red[1][3];
      qstats[bi * 3 + 2] = red[2][0] + red[2][1] + red[2][2] + red[2][3];
    }
  } else {
    int wb = blockIdx.x - 1024;  // 0..11
    int plane = wb >> 1, half = wb & 1;
    int k = half * 1024 + t * 4;
    float4 v;
    if (plane == 0) {
      v = *(const float4*)(w_cq + k);
    } else if (plane == 3) {
      v = *(const float4*)(w_c + k);
    } else {
      const float* s;
      if (plane == 1)
        s = W_out + (size_t)(2 * D + k) * 2;
      else if (plane == 2)
        s = W_out + (size_t)(2 * D + k) * 2 + 1;
      else if (plane == 4)
        s = W_out + (size_t)k * 2;
      else
        s = W_out + (size_t)k * 2 + 1;
      v = make_float4(s[0], s[2], s[4], s[6]);
    }
    *(float4*)(wpack + plane * 2048 + k) = v;
  }
}

// ---------------- kernel 1: transposed split-K MFMA score GEMM --------------
// Champion structure (r18/r21): in-kernel pack from q x wpack-LDS, 4 LDS
// buffers, depth-2 reg prefetch, 1 barrier/step. Side-product cbf now FP8
// (tail-only; scores remain bf16-MFMA).
__global__ __launch_bounds__(512, 1) void k_score(
    const float* __restrict__ wpack, const float* __restrict__ q,
    const float* __restrict__ c, unsigned short* __restrict__ S3pb,
    unsigned char* __restrict__ cbf8) {
  const int t = threadIdx.x;
  const int lane = t & 63, wv = t >> 6;
  const int bid = blockIdx.x;
  const int b = bid & 15, kcb = (bid >> 4) & 3, n0 = (bid >> 6) * NT;
  const int lr = lane & 15, lg = lane >> 4;
  const int mg = wv >> 1, ng = wv & 1;

  __shared__ unsigned short sBp[4][IST];        // 4 x 16640 B (pack)
  __shared__ unsigned short sCp[4][NT * PITCH]; // 4 x 7680 B  (c rows)
  __shared__ float wL[6 * 512];                 // 12 KB w-table (kcb slice)

  {
    int p = t >> 7, j4 = (t & 127) * 4;
    GLD_LDS(wpack + p * 2048 + kcb * 512 + j4, wL + p * 512 + j4);
    if (t < 256) {
      int c2 = 512 + t;
      int p2 = c2 >> 7, k4 = (c2 & 127) * 4;
      GLD_LDS(wpack + p2 * 2048 + kcb * 512 + k4, wL + p2 * 512 + k4);
    }
  }
  asm volatile("s_waitcnt vmcnt(0)" ::: "memory");
  __builtin_amdgcn_s_barrier();

  const float* cbase = c + ((size_t)b * C + n0) * D + kcb * 512;
  unsigned char* cbf_base = cbf8 + ((size_t)b * C + n0) * D + kcb * 512;
  const int qi = t >> 3, qkc = (t & 7) * 4;
  const float* qbase = q + ((size_t)b * Q + qi) * D + kcb * 512 + qkc;

  f32x4 acc[4][3];
#pragma unroll
  for (int f = 0; f < 4; ++f)
#pragma unroll
    for (int g = 0; g < 3; ++g) acc[f][g] = f32x4{0.f, 0.f, 0.f, 0.f};

  auto loadQ = [&](float4& r, int s) {
    r = *(const float4*)(qbase + s * 32);
  };
  auto loadC = [&](float4* r, int s) {
    const float* base = cbase + s * 32;
    if (wv < 4) {
      int g0 = wv * 128 + lane;
      r[0] = *(const float4*)(base + (size_t)(g0 >> 3) * D + (g0 & 7) * 4);
      int g1 = g0 + 64;
      r[1] = *(const float4*)(base + (size_t)(g1 >> 3) * D + (g1 & 7) * 4);
    } else {
      int g0 = 512 + (wv - 4) * 64 + lane;
      r[0] = *(const float4*)(base + (size_t)(g0 >> 3) * D + (g0 & 7) * 4);
    }
  };
  auto writeB = [&](int buf, const float4& rq, int s) {
    int ko = s * 32 + qkc;
    float4 w0 = *(const float4*)&wL[ko];
    float4 w1 = *(const float4*)&wL[512 + ko];
    float4 w2 = *(const float4*)&wL[1024 + ko];
    uint2 u;
    u.x = pkbf(rq.x * w0.x, rq.y * w0.y);
    u.y = pkbf(rq.z * w0.z, rq.w * w0.w);
    *(uint2*)&sBp[buf][qi * PITCH + qkc] = u;
    u.x = pkbf(rq.x * w1.x, rq.y * w1.y);
    u.y = pkbf(rq.z * w1.z, rq.w * w1.w);
    *(uint2*)&sBp[buf][(64 + qi) * PITCH + qkc] = u;
    u.x = pkbf(rq.x * w2.x, rq.y * w2.y);
    u.y = pkbf(rq.z * w2.z, rq.w * w2.w);
    *(uint2*)&sBp[buf][(128 + qi) * PITCH + qkc] = u;
    if (t < 24) {  // stats rows 192..194 from planes 3..5
      int r = t >> 3, kc2 = (t & 7) * 4;
      float4 wv4 = *(const float4*)&wL[(3 + r) * 512 + s * 32 + kc2];
      uint2 us;
      us.x = pkbf(wv4.x, wv4.y);
      us.y = pkbf(wv4.z, wv4.w);
      *(uint2*)&sBp[buf][(192 + r) * PITCH + kc2] = us;
    }
  };
  auto writeC = [&](int buf, const float4* r, int s) {
    unsigned char* cb = cbf_base + s * 32;
    if (wv < 4) {
      int g0 = wv * 128 + lane;
      uint2 u0 = {pkbf(r[0].x, r[0].y), pkbf(r[0].z, r[0].w)};
      *(uint2*)&sCp[buf][(g0 >> 3) * PITCH + (g0 & 7) * 4] = u0;
      *(unsigned*)(cb + (size_t)(g0 >> 3) * D + (g0 & 7) * 4) = pk8(r[0]);
      int g1 = g0 + 64;
      uint2 u1 = {pkbf(r[1].x, r[1].y), pkbf(r[1].z, r[1].w)};
      *(uint2*)&sCp[buf][(g1 >> 3) * PITCH + (g1 & 7) * 4] = u1;
      *(unsigned*)(cb + (size_t)(g1 >> 3) * D + (g1 & 7) * 4) = pk8(r[1]);
    } else {
      int g0 = 512 + (wv - 4) * 64 + lane;
      uint2 u0 = {pkbf(r[0].x, r[0].y), pkbf(r[0].z, r[0].w)};
      *(uint2*)&sCp[buf][(g0 >> 3) * PITCH + (g0 & 7) * 4] = u0;
      *(unsigned*)(cb + (size_t)(g0 >> 3) * D + (g0 & 7) * 4) = pk8(r[0]);
    }
  };
  auto compute = [&](int buf) {
    s16x8 af[4], bf[3];
#pragma unroll
    for (int f = 0; f < 4; ++f)
      af[f] = *(const s16x8*)&sBp[buf][(mg * 64 + f * 16 + lr) * PITCH +
                                       lg * 8];
#pragma unroll
    for (int g = 0; g < 3; ++g)
      bf[g] = *(const s16x8*)&sCp[buf][((ng * 3 + g) * 16 + lr) * PITCH +
                                       lg * 8];
    __builtin_amdgcn_s_setprio(1);
#pragma unroll
    for (int f = 0; f < 4; ++f)
#pragma unroll
      for (int g = 0; g < 3; ++g)
        acc[f][g] =
            __builtin_amdgcn_mfma_f32_16x16x32_bf16(af[f], bf[g], acc[f][g],
                                                    0, 0, 0);
    __builtin_amdgcn_s_setprio(0);
  };

  float4 rc[4][2], rq[4];
  loadC(rc[0], 0);
  loadQ(rq[0], 0);
  loadC(rc[1], 1);
  loadQ(rq[1], 1);
#pragma unroll
  for (int s = 0; s < 16; ++s) {
    const int cur = s & 3;
    if (s + 2 < 16) {
      loadC(rc[(s + 2) & 3], s + 2);
      loadQ(rq[(s + 2) & 3], s + 2);
    }
    writeB(cur, rq[cur], s);
    writeC(cur, rc[cur], s);
    asm volatile("s_waitcnt lgkmcnt(0)" ::: "memory");
    __builtin_amdgcn_sched_barrier(0);
    __builtin_amdgcn_s_barrier();  // publish buffers(cur); bounds skew to 1
    compute(cur);
    // no trailing barrier: reuse distance 4 steps, skew <= 1 step
  }

  // epilogue: bf16-pack real frags (mf < 13) to this kc's partial buffer
  const size_t rowbase = ((size_t)kcb * B + b) * C;
#pragma unroll
  for (int f = 0; f < 4; ++f) {
    int mf = mg * 4 + f;
    if (mf < 13) {
#pragma unroll
      for (int g = 0; g < 3; ++g) {
        int n = n0 + (ng * 3 + g) * 16 + lr;
        uint2 pk;
        pk.x = pkbf(acc[f][g][0], acc[f][g][1]);
        pk.y = pkbf(acc[f][g][2], acc[f][g][3]);
        *(uint2*)(S3pb + (rowbase + n) * SP + mf * 16 + lg * 4) = pk;
      }
    }
  }
}

// ---------------- kernel 2: sum partials + row softmax + reductions ---------
__global__ __launch_bounds__(256) void k_soft(
    const unsigned short* __restrict__ S3pb, const float* __restrict__ qstats,
    const int* __restrict__ c_len, const int* __restrict__ q_len,
    const float* __restrict__ b_c, const float* __restrict__ b_q,
    const float* __restrict__ b_cq, float* __restrict__ mrow,
    float* __restrict__ out12) {
  const int t = threadIdx.x, lane = t & 63;
  const int rg = blockIdx.x * 4 + (t >> 6);  // b*C + r
  const int b = rg / C, r = rg % C;
  float s_cq = 0.f, sc = 0.f, w10 = 0.f, w11 = 0.f, t30 = 0.f, t31 = 0.f;
#pragma unroll
  for (int p = 0; p < KC; ++p) {
    const unsigned short* Sr = S3pb + ((size_t)p * B * C + rg) * SP;
    s_cq += bfs(Sr[lane]);
    sc += bfs(Sr[192]);
    w10 += bfs(Sr[193]);
    w11 += bfs(Sr[194]);
    t30 += bfs(Sr[64 + lane]);
    t31 += bfs(Sr[128 + lane]);
  }
  const float qs0 = qstats[((b << 6) + lane) * 3 + 0];
  const float qs1 = qstats[((b << 6) + lane) * 3 + 1];
  const float qs2 = qstats[((b << 6) + lane) * 3 + 2];
  float s = s_cq + sc + qs0 + b_c[0] + b_q[0] + b_cq[0];
  const int cl = c_len[b], ql = q_len[b];
  bool masked = (lane >= ql) || ((r >= cl) && (lane < Q - 1));
  if (masked) s += NEGV;
  float mx = s;
  for (int m = 1; m < 64; m <<= 1) mx = fmaxf(mx, __shfl_xor(mx, m, 64));
  float e = __expf(s - mx);
  float den = e;
  for (int m = 1; m < 64; m <<= 1) den += __shfl_xor(den, m, 64);
  float a = e / den;
  float v0 = a * (qs1 + t30);
  float v1 = a * (qs2 + t31);
  for (int m = 1; m < 64; m <<= 1) {
    v0 += __shfl_xor(v0, m, 64);
    v1 += __shfl_xor(v1, m, 64);
  }
  if (lane == 0) {
    mrow[rg] = mx;
    out12[rg * 2 + 0] = w10 + v0;
    out12[rg * 2 + 1] = w11 + v1;
  }
}

// ---------------- kernel 3: q2c GEMV (fp8 c) fused with W4 -> u vectors -----
// grid (16 d-chunks of 128, B), 512 thr. thread = (row-group rg 0..15,
// d-lane dl 0..31, 4 d each). u[d,:] = q2c[d]*W4[d,:].
__global__ __launch_bounds__(512) void k_q2cu(
    const unsigned char* __restrict__ cbf8, const float* __restrict__ mrow,
    const float* __restrict__ W_out, float* __restrict__ uvec) {
  const int ch = blockIdx.x, b = blockIdx.y;
  const int t = threadIdx.x, lane = t & 63, wv = t >> 6;
  __shared__ float batt[C];
  __shared__ float rmx[8], rsm[8];
  __shared__ float4 red4[16][32];

  float m = (t < C) ? mrow[b * C + t] : -3.0e38f;
  float mx = m;
  for (int o = 1; o < 64; o <<= 1) mx = fmaxf(mx, __shfl_xor(mx, o, 64));
  if (lane == 0) rmx[wv] = mx;
  __syncthreads();
  mx = rmx[0];
#pragma unroll
  for (int i = 1; i < 8; ++i) mx = fmaxf(mx, rmx[i]);
  float e = (t < C) ? __expf(m - mx) : 0.f;
  float sm = e;
  for (int o = 1; o < 64; o <<= 1) sm += __shfl_xor(sm, o, 64);
  if (lane == 0) rsm[wv] = sm;
  __syncthreads();
  sm = rsm[0] + rsm[1] + rsm[2] + rsm[3] + rsm[4] + rsm[5] + rsm[6] + rsm[7];
  if (t < C) batt[t] = e / sm;
  __syncthreads();

  const int dl = t & 31, rg = t >> 5;  // 16 row-groups x 24 rows
  const int d0 = ch * 128 + dl * 4;
  const unsigned char* p = cbf8 + ((size_t)b * C + rg * 24) * D + d0;
  float4 A = {0.f, 0.f, 0.f, 0.f};
#pragma unroll
  for (int j = 0; j < 24; ++j) {
    unsigned cc = *(const unsigned*)(p + (size_t)j * D);
    f32x2 lo = __builtin_amdgcn_cvt_pk_f32_fp8(cc, false);
    f32x2 hi = __builtin_amdgcn_cvt_pk_f32_fp8(cc, true);
    float w = batt[rg * 24 + j];
    A.x += w * lo.x;
    A.y += w * lo.y;
    A.z += w * hi.x;
    A.w += w * hi.y;
  }
  red4[rg][dl] = A;
  __syncthreads();
  if (t < 32) {
    float4 qv = {0.f, 0.f, 0.f, 0.f};
#pragma unroll
    for (int g = 0; g < 16; ++g) {
      float4 v = red4[g][t];
      qv.x += v.x;
      qv.y += v.y;
      qv.z += v.z;
      qv.w += v.w;
    }
    int dd = ch * 128 + t * 4;
    const float* wp = W_out + (size_t)(3 * D + dd) * 2;
    float4 wa = *(const float4*)(wp);
    float4 wb = *(const float4*)(wp + 4);
    float4 u0 = {qv.x * wa.x, qv.x * wa.y, qv.y * wa.z, qv.y * wa.w};
    float4 u1 = {qv.z * wb.x, qv.z * wb.y, qv.w * wb.z, qv.w * wb.w};
    *(float4*)(uvec + ((size_t)b * D + dd) * 2) = u0;
    *(float4*)(uvec + ((size_t)b * D + dd) * 2 + 4) = u1;
  }
}

// ---------------- kernel 4: term4 row-dots (fp8 c) + bias + mask + write ----
// grid (C/8=48, B), 512 thr (8 waves), wave per row; u staged in LDS.
__global__ __launch_bounds__(512) void k_out(
    const unsigned char* __restrict__ cbf8, const float* __restrict__ uvec,
    const float* __restrict__ out12, const float* __restrict__ b_out,
    const int* __restrict__ c_len, float* __restrict__ outp) {
  const int b = blockIdx.y, r0 = blockIdx.x * 8;
  const int t = threadIdx.x, lane = t & 63, wv = t >> 6;
  __shared__ float u_sh[2 * D];  // interleaved {u0,u1} pairs

  {
    const float* src = uvec + (size_t)b * D * 2 + t * 8;
    float4 v0 = *(const float4*)(src);
    float4 v1 = *(const float4*)(src + 4);
    *(float4*)&u_sh[t * 8] = v0;
    *(float4*)&u_sh[t * 8 + 4] = v1;
  }
  __syncthreads();

  const int r = r0 + wv;
  const unsigned char* crow = cbf8 + ((size_t)b * C + r) * D;
  float o0 = 0.f, o1 = 0.f;
#pragma unroll
  for (int it = 0; it < 8; ++it) {
    int d0 = it * 256 + lane * 4;
    unsigned cc = *(const unsigned*)(crow + d0);
    f32x2 lo = __builtin_amdgcn_cvt_pk_f32_fp8(cc, false);
    f32x2 hi = __builtin_amdgcn_cvt_pk_f32_fp8(cc, true);
    float4 ua = *(const float4*)&u_sh[d0 * 2];
    float4 ub = *(const float4*)&u_sh[d0 * 2 + 4];
    o0 += lo.x * ua.x + lo.y * ua.z + hi.x * ub.x + hi.y * ub.z;
    o1 += lo.x * ua.y + lo.y * ua.w + hi.x * ub.y + hi.y * ub.w;
  }
  for (int o = 1; o < 64; o <<= 1) {
    o0 += __shfl_xor(o0, o, 64);
    o1 += __shfl_xor(o1, o, 64);
  }
  if (lane == 0) {
    const int idx = b * C + r;
    o0 += out12[idx * 2 + 0] + b_out[0];
    o1 += out12[idx * 2 + 1] + b_out[1];
    if (r >= c_len[b] && r < C - 1) { o0 = NEGV; o1 = NEGV; }
    outp[idx] = o0;
    outp[B * C + idx] = o1;
  }
}

extern "C" void kernel_launch(void* const* d_in, const int* in_sizes, int n_in,
                              void* d_out, int out_size, void* d_ws,
                              size_t ws_size, hipStream_t stream) {
  const float* c = (const float*)d_in[0];
  const float* q = (const float*)d_in[1];
  const int* c_len = (const int*)d_in[2];
  const int* q_len = (const int*)d_in[3];
  const float* w_c = (const float*)d_in[4];
  const float* b_c = (const float*)d_in[5];
  const float* w_q = (const float*)d_in[6];
  const float* b_q = (const float*)d_in[7];
  const float* w_cq = (const float*)d_in[8];
  const float* b_cq = (const float*)d_in[9];
  const float* W_out = (const float*)d_in[10];
  const float* b_out = (const float*)d_in[11];
  float* outp = (float*)d_out;

  // ws: wpack (48 KB) | S3 partials bf16 (10.2 MB) | smalls | uvec | cbf8
  float* wpack = (float*)d_ws;  // 6 * 2048 f32
  unsigned short* S3pb = (unsigned short*)(wpack + 6 * 2048);
  const size_t s3_elems = (size_t)KC * B * C * SP;  // 5,111,808 shorts
  float* ws = (float*)(S3pb + s3_elems);
  float* qstats = ws;                      // B*Q*3  = 3072
  float* mrow = ws + 3072;                 // B*C    = 6144
  float* out12 = ws + 3072 + 6144;         // B*C*2  = 12288
  float* uvec = ws + 3072 + 6144 + 12288;  // B*D*2  = 65536
  unsigned char* cbf8 = (unsigned char*)(uvec + 65536);  // B*C*D fp8

  hipLaunchKernelGGL(k_prep, dim3(1024 + 12), dim3(256), 0, stream, q, w_q,
                     w_cq, w_c, W_out, qstats, wpack);
  hipLaunchKernelGGL(k_score, dim3(4 * KC * B), dim3(512), 0, stream, wpack,
                     q, c, S3pb, cbf8);
  hipLaunchKernelGGL(k_soft, dim3(B * C / 4), dim3(256), 0, stream, S3pb,
                     qstats, c_len, q_len, b_c, b_q, b_cq, mrow, out12);
  hipLaunchKernelGGL(k_q2cu, dim3(16, B), dim3(512), 0, stream, cbf8, mrow,
                     W_out, uvec);
  hipLaunchKernelGGL(k_out, dim3(C / 8, B), dim3(512), 0, stream, cbf8, uvec,
                     out12, b_out, c_len, outp);
}